// Round 3
// baseline (3810.594 us; speedup 1.0000x reference)
//
#include <hip/hip_runtime.h>
#include <hip/hip_bf16.h>
#include <math.h>

// Problem constants
#define Bn 64
#define Tn 512
#define In 256
#define Hn 1024
#define Fn 11
#define TP1 513       // T+1 slots in r history (slot 0 = h0)
#define SENT32 0x7FC07FC0u
#define SENT64 0x7FC07FC07FC07FC0ull

typedef __attribute__((ext_vector_type(8))) short short8;  // 8 bf16 (4 VGPRs)
typedef __attribute__((ext_vector_type(4))) float f32x4;
typedef unsigned short u16;
typedef unsigned int u32;
typedef unsigned long long u64;
typedef __hip_bfloat16 bf16;

__device__ __forceinline__ float sigm(float x) { return 1.0f / (1.0f + __expf(-x)); }
__device__ __forceinline__ short8 ld8(const bf16* p) { return *(const short8*)p; }

// normal vector load with NaN-sentinel check; falls back to IF-coherent reload
__device__ __forceinline__ short8 ldA_chk(const bf16* p) {
  short8 v = *(const short8*)p;
  u32* c = (u32*)&v;
  bool bad = (c[0] == SENT32) | (c[1] == SENT32) | (c[2] == SENT32) | (c[3] == SENT32);
  while (__ballot(bad)) {
    if (bad) {
#pragma unroll
      for (int i = 0; i < 4; ++i)
        c[i] = __hip_atomic_load((u32*)p + i, __ATOMIC_RELAXED, __HIP_MEMORY_SCOPE_AGENT);
      bad = (c[0] == SENT32) | (c[1] == SENT32) | (c[2] == SENT32) | (c[3] == SENT32);
    }
  }
  return v;
}

// ---------------- cast inputs to bf16, init rb: slot0=h0, slots 1..T=sentinel ----------------
__global__ void k_cast(const float* __restrict__ x, const float* __restrict__ whh,
                       const float* __restrict__ wih, const float* __restrict__ h0,
                       bf16* __restrict__ xb, bf16* __restrict__ whhb,
                       bf16* __restrict__ wihb, bf16* __restrict__ rb)
{
  const long N0 = 8388608L;                 // x: B*T*I
  const long N1 = N0 + 4194304L;            // W_hh: 4H*H
  const long N2 = N1 + 1048576L;            // W_ih: 4H*I
  const long N3 = N2 + 65536L;              // h0 -> rb slot 0
  const long N4 = N3 + 8388608L;            // rb slots 1..T sentinel (u64 stores)
  long i = (long)blockIdx.x * 256 + threadIdx.x;
  if (i < N0) {
    xb[i] = __float2bfloat16(x[i]);
  } else if (i < N1) {
    long j = i - N0; whhb[j] = __float2bfloat16(whh[j]);
  } else if (i < N2) {
    long j = i - N1; wihb[j] = __float2bfloat16(wih[j]);
  } else if (i < N3) {
    long j = i - N2;
    int b = (int)(j >> 10), h = (int)(j & 1023);
    rb[((long)b * TP1) * Hn + h] = __float2bfloat16(h0[j]);
  } else if (i < N4) {
    long j = i - N3;                        // u64 index over B * T * (H/4)
    long b = j >> 17;                       // 512*256 = 2^17 u64 per batch
    long rem = j & 131071L;
    long s = (rem >> 8) + 1;                // slot 1..512
    long c = rem & 255L;
    ((u64*)rb)[((long)b * TP1 + s) * 256 + c] = SENT64;
  }
}

// ---------------- fold post-LSTM linears: Gb[16][H] = V @ W_sh (bf16), cv[16] ----------------
// rows 0..10: W_state, 11: W_reward, 12: w_att_s, 13: w_att_r, 14/15: zero
__global__ void k_fold(const float* __restrict__ Wsh, const float* __restrict__ Wst,
                       const float* __restrict__ Wrw, const float* __restrict__ was,
                       const float* __restrict__ war, const float* __restrict__ bsh,
                       const float* __restrict__ bst, const float* __restrict__ brw,
                       const float* __restrict__ bas, const float* __restrict__ barr,
                       bf16* __restrict__ Gb, float* __restrict__ cv)
{
  const int tid = threadIdx.x;
  const int kblk = blockIdx.x;              // 4
  const int j = blockIdx.y;                 // 16
  const int k = kblk * 256 + tid;
  const float* V = nullptr; float bb = 0.f;
  if (j < 11)      { V = Wst + j * Hn; bb = bst[j]; }
  else if (j == 11){ V = Wrw;          bb = brw[0]; }
  else if (j == 12){ V = was;          bb = bas[0]; }
  else if (j == 13){ V = war;          bb = barr[0]; }
  float acc = 0.f;
  if (V) for (int h = 0; h < Hn; ++h) acc += V[h] * Wsh[(long)h * Hn + k];
  Gb[j * Hn + k] = __float2bfloat16(acc);
  if (kblk == 0) {
    __shared__ float red[256];
    float p = 0.f;
    if (V) for (int h = tid; h < Hn; h += 256) p += bsh[h] * V[h];
    red[tid] = p; __syncthreads();
    for (int s = 128; s > 0; s >>= 1) { if (tid < s) red[tid] += red[tid + s]; __syncthreads(); }
    if (tid == 0) cv[j] = red[0] + bb;
  }
}

// ---------------- LSTM: persistent coop kernel; sentinel-poll exchange; proj fused in tail ----------------
// 4 batch-groups x 64 WGs. WG owns 16 h-dims. Waves split K (8 h-kbs + 2 x-kbs each).
// A-fragments loaded directly from IF (relaxed agent, polled on NaN sentinel) -> no flags, no staging.
__global__ void __launch_bounds__(256, 1)
k_lstm(const bf16* __restrict__ xb, const bf16* __restrict__ whhb,
       const bf16* __restrict__ wihb, const float* __restrict__ bih,
       const float* __restrict__ bhh, const float* __restrict__ c0,
       bf16* __restrict__ rb, const bf16* __restrict__ Gb,
       const float* __restrict__ cv, float* __restrict__ P,
       float* __restrict__ outH, float* __restrict__ outC)
{
  const int tid = threadIdx.x;
  const int w = tid >> 6, l = tid & 63;
  const int lo16 = l & 15, q = l >> 4;
  const int g = blockIdx.x >> 6;       // batch group 0..3 (16 batches each)
  const int mem = blockIdx.x & 63;     // member in group
  const int bG0 = g << 4;
  const int wrow = (mem << 4) + lo16;  // this lane's weight row (within each gate)

  // B-fragments in registers: wf[gate][0..7]=h kbs (w*8+kk), wf[gate][8..9]=x kbs (w*2+kk)
  short8 wf[4][10];
#pragma unroll
  for (int j = 0; j < 4; ++j) {
#pragma unroll
    for (int kk = 0; kk < 8; ++kk)
      wf[j][kk] = ld8(whhb + ((long)(j * Hn + wrow)) * Hn + (w * 8 + kk) * 32 + q * 8);
#pragma unroll
    for (int kk = 0; kk < 2; ++kk)
      wf[j][8 + kk] = ld8(wihb + ((long)(j * Hn + wrow)) * In + (w * 2 + kk) * 32 + q * 8);
  }

  // gate-phase mapping: thread -> (batch bl, local dim diml)
  const int bl = tid & 15, diml = tid >> 4;
  const int bb = bG0 + bl;
  const int dloc = (mem << 4) + diml;
  const float bi0 = bih[dloc]          + bhh[dloc];
  const float bi1 = bih[Hn + dloc]     + bhh[Hn + dloc];
  const float bi2 = bih[2 * Hn + dloc] + bhh[2 * Hn + dloc];
  const float bi3 = bih[3 * Hn + dloc] + bhh[3 * Hn + dloc];
  float cst = c0[(long)bb * Hn + dloc];

  // per-lane A-fragment bases
  const bf16* xA = xb + ((long)(bG0 + lo16)) * Tn * In + (w * 2) * 32 + q * 8;
  const u64*  rA = (const u64*)rb + ((long)(bG0 + lo16)) * TP1 * 256 + (w * 8) * 8 + q * 2;

  __shared__ float zbuf[4][4][16][17];   // [K-quarter wave][gate][dim lo16][batch+pad]

  for (int t = 0; t < Tn; ++t) {
    // x fragments + x-part MFMA first (recurrence-independent -> fills poll shadow)
    const short8 xf0 = ld8(xA + (long)t * In);
    const short8 xf1 = ld8(xA + (long)t * In + 32);
    f32x4 a0 = {0,0,0,0}, a1 = {0,0,0,0}, a2 = {0,0,0,0}, a3 = {0,0,0,0};
    a0 = __builtin_amdgcn_mfma_f32_16x16x32_bf16(xf0, wf[0][8], a0, 0, 0, 0);
    a1 = __builtin_amdgcn_mfma_f32_16x16x32_bf16(xf0, wf[1][8], a1, 0, 0, 0);
    a2 = __builtin_amdgcn_mfma_f32_16x16x32_bf16(xf0, wf[2][8], a2, 0, 0, 0);
    a3 = __builtin_amdgcn_mfma_f32_16x16x32_bf16(xf0, wf[3][8], a3, 0, 0, 0);
    a0 = __builtin_amdgcn_mfma_f32_16x16x32_bf16(xf1, wf[0][9], a0, 0, 0, 0);
    a1 = __builtin_amdgcn_mfma_f32_16x16x32_bf16(xf1, wf[1][9], a1, 0, 0, 0);
    a2 = __builtin_amdgcn_mfma_f32_16x16x32_bf16(xf1, wf[2][9], a2, 0, 0, 0);
    a3 = __builtin_amdgcn_mfma_f32_16x16x32_bf16(xf1, wf[3][9], a3, 0, 0, 0);

    // poll this lane's h fragments (data IS the flag: NaN sentinel until written)
    const u64* rp = rA + (long)t * 256;
    u64 hv[16];
    u32 pend = 0xFFFFu;
    while (true) {
#pragma unroll
      for (int i = 0; i < 16; ++i)
        if ((pend >> i) & 1u)
          hv[i] = __hip_atomic_load((u64*)(rp + (i >> 1) * 8 + (i & 1)),
                                    __ATOMIC_RELAXED, __HIP_MEMORY_SCOPE_AGENT);
      u32 np = 0;
#pragma unroll
      for (int i = 0; i < 16; ++i)
        if ((pend >> i) & 1u) {
          u32 lo = (u32)hv[i], hi = (u32)(hv[i] >> 32);
          if (lo == SENT32 || hi == SENT32) np |= 1u << i;
        }
      pend = np;
      if (__ballot(pend != 0u) == 0ULL) break;
    }

    // h-part MFMA
#pragma unroll
    for (int kk = 0; kk < 8; ++kk) {
      union { u64 d[2]; short8 s; } u;
      u.d[0] = hv[2 * kk]; u.d[1] = hv[2 * kk + 1];
      a0 = __builtin_amdgcn_mfma_f32_16x16x32_bf16(u.s, wf[0][kk], a0, 0, 0, 0);
      a1 = __builtin_amdgcn_mfma_f32_16x16x32_bf16(u.s, wf[1][kk], a1, 0, 0, 0);
      a2 = __builtin_amdgcn_mfma_f32_16x16x32_bf16(u.s, wf[2][kk], a2, 0, 0, 0);
      a3 = __builtin_amdgcn_mfma_f32_16x16x32_bf16(u.s, wf[3][kk], a3, 0, 0, 0);
    }

    // cross-wave K reduction via LDS
    __syncthreads();                       // prior gates reads done before overwrite
#pragma unroll
    for (int r = 0; r < 4; ++r) {
      zbuf[w][0][lo16][q * 4 + r] = a0[r];
      zbuf[w][1][lo16][q * 4 + r] = a1[r];
      zbuf[w][2][lo16][q * 4 + r] = a2[r];
      zbuf[w][3][lo16][q * 4 + r] = a3[r];
    }
    __syncthreads();

    float zi = zbuf[0][0][diml][bl] + zbuf[1][0][diml][bl] + zbuf[2][0][diml][bl] + zbuf[3][0][diml][bl] + bi0;
    float zf = zbuf[0][1][diml][bl] + zbuf[1][1][diml][bl] + zbuf[2][1][diml][bl] + zbuf[3][1][diml][bl] + bi1;
    float zg = zbuf[0][2][diml][bl] + zbuf[1][2][diml][bl] + zbuf[2][2][diml][bl] + zbuf[3][2][diml][bl] + bi2;
    float zo = zbuf[0][3][diml][bl] + zbuf[1][3][diml][bl] + zbuf[2][3][diml][bl] + zbuf[3][3][diml][bl] + bi3;
    float iv = sigm(zi), fv = sigm(zf), gv = tanhf(zg), ov = sigm(zo);
    cst = fv * cst + iv * gv;
    float hv_ = ov * tanhf(cst);

    // packed u32 h store, relaxed agent -> IF; data arrival IS the signal
    float ph = __shfl_xor(hv_, 16, 64);          // partner has diml^1
    u16 mb = __builtin_bit_cast(u16, __float2bfloat16(hv_));
    u16 pb = __builtin_bit_cast(u16, __float2bfloat16(ph));
    if ((diml & 1) == 0) {
      u32 pack = (u32)mb | ((u32)pb << 16);
      u32* dst = (u32*)(rb + ((long)bb * TP1 + t + 1) * Hn + dloc);
      __hip_atomic_store(dst, pack, __ATOMIC_RELAXED, __HIP_MEMORY_SCOPE_AGENT);
    }
    if (t == Tn - 1) {
      outH[(long)bb * Hn + dloc] = hv_;
      outC[(long)bb * Hn + dloc] = cst;
    }
  }

  // -------- fused projection tail: this group's 8192 (b,t) rows onto Gb[16] basis --------
  const bf16* gp = Gb + (long)lo16 * Hn + q * 8;
#pragma unroll
  for (int pass = 0; pass < 2; ++pass) {
    const int tilebase = mem * 128 + pass * 64 + w * 16;
    const int rl = tilebase + lo16;
    const int pb_ = rl >> 9, pt = rl & 511;
    const bf16* ap = rb + ((long)(bG0 + pb_) * TP1 + pt + 1) * Hn + q * 8;
    f32x4 c0a = {0,0,0,0}, c1a = {0,0,0,0};
#pragma unroll
    for (int kb = 0; kb < 32; kb += 2) {
      short8 af0 = ldA_chk(ap + kb * 32);
      short8 af1 = ldA_chk(ap + kb * 32 + 32);
      c0a = __builtin_amdgcn_mfma_f32_16x16x32_bf16(af0, ld8(gp + kb * 32),      c0a, 0, 0, 0);
      c1a = __builtin_amdgcn_mfma_f32_16x16x32_bf16(af1, ld8(gp + kb * 32 + 32), c1a, 0, 0, 0);
    }
    f32x4 z = c0a + c1a;
    float cc = cv[lo16];
    const long prow = (long)bG0 * 512 + tilebase;
#pragma unroll
    for (int r = 0; r < 4; ++r)
      P[(prow + q * 4 + r) * 16 + lo16] = z[r] + cc;
  }
}

// ---------------- per-batch online-softmax prefix scan ----------------
__global__ void k_scan(const float* __restrict__ P, float* __restrict__ outS,
                       float* __restrict__ outR)
{
  __shared__ float sp[Tn * 16];
  const int b = blockIdx.x, tid = threadIdx.x;
  for (int i = tid; i < Tn * 16; i += 64) sp[i] = P[(long)b * Tn * 16 + i];
  __syncthreads();
  const int j = tid;
  if (j < 12) {
    const bool isR = (j == 11);
    float m = -INFINITY, den = 0.f, num = 0.f;
    for (int t = 0; t < Tn; ++t) {
      float val = sp[t * 16 + j];
      float ll = sp[t * 16 + (isR ? 13 : 12)];
      float mn = fmaxf(m, ll);
      float al = __expf(m - mn);
      float e  = __expf(ll - mn);
      den = den * al + e;
      num = num * al + e * val;
      m = mn;
      float o = num / den;
      if (isR) outR[(long)b * Tn + t] = o;
      else     outS[(long)(b * Tn + t) * Fn + j] = o;
    }
  }
}

extern "C" void kernel_launch(void* const* d_in, const int* in_sizes, int n_in,
                              void* d_out, int out_size, void* d_ws, size_t ws_size,
                              hipStream_t stream)
{
  (void)in_sizes; (void)n_in; (void)out_size; (void)ws_size;
  const float* x    = (const float*)d_in[0];
  const float* h0   = (const float*)d_in[2];
  const float* c0   = (const float*)d_in[3];
  const float* Wih  = (const float*)d_in[4];
  const float* Whh  = (const float*)d_in[5];
  const float* bih  = (const float*)d_in[6];
  const float* bhh  = (const float*)d_in[7];
  const float* Wsh  = (const float*)d_in[8];
  const float* bsh  = (const float*)d_in[9];
  const float* was  = (const float*)d_in[10];
  const float* bas  = (const float*)d_in[11];
  const float* war  = (const float*)d_in[12];
  const float* barr = (const float*)d_in[13];
  const float* Wst  = (const float*)d_in[14];
  const float* bst  = (const float*)d_in[15];
  const float* Wrw  = (const float*)d_in[16];
  const float* brw  = (const float*)d_in[17];

  char* ws = (char*)d_ws;
  size_t off = 0;
  auto alloc = [&](size_t bytes) -> void* {
    void* p = ws + off; off += (bytes + 255) & ~(size_t)255; return p;
  };
  bf16* xb    = (bf16*)alloc((size_t)Bn * Tn * In * 2);
  bf16* whhb  = (bf16*)alloc((size_t)4 * Hn * Hn * 2);
  bf16* wihb  = (bf16*)alloc((size_t)4 * Hn * In * 2);
  bf16* rb    = (bf16*)alloc((size_t)Bn * TP1 * Hn * 2);
  bf16* Gb    = (bf16*)alloc((size_t)16 * Hn * 2);
  float* cv   = (float*)alloc(16 * 4);
  float* P    = (float*)alloc((size_t)Bn * Tn * 16 * 4);

  float* outS = (float*)d_out;
  float* outR = outS + (size_t)Bn * Tn * Fn;
  float* outH = outR + (size_t)Bn * Tn;
  float* outC = outH + (size_t)Bn * Hn;

  const long NCAST = 8388608L + 4194304L + 1048576L + 65536L + 8388608L;
  k_cast<<<dim3((unsigned)(NCAST / 256)), 256, 0, stream>>>(x, Whh, Wih, h0, xb, whhb, wihb, rb);
  k_fold<<<dim3(4, 16), 256, 0, stream>>>(Wsh, Wst, Wrw, was, war, bsh, bst, brw, bas, barr, Gb, cv);

  {
    void* args[] = { (void*)&xb, (void*)&whhb, (void*)&wihb, (void*)&bih, (void*)&bhh,
                     (void*)&c0, (void*)&rb, (void*)&Gb, (void*)&cv, (void*)&P,
                     (void*)&outH, (void*)&outC };
    hipError_t e = hipLaunchCooperativeKernel((const void*)k_lstm, dim3(256), dim3(256),
                                              args, 0, stream);
    if (e != hipSuccess) {
      k_lstm<<<256, 256, 0, stream>>>(xb, whhb, wihb, bih, bhh, c0, rb, Gb, cv, P, outH, outC);
    }
  }

  k_scan<<<64, 64, 0, stream>>>(P, outS, outR);
}